// Round 21
// baseline (231.400 us; speedup 1.0000x reference)
//
#include <hip/hip_runtime.h>

#define NB 4
#define NS 2048
#define NE 1024
#define NH 16
#define ND 64
#define KVB 64

typedef unsigned short ushort_t;
typedef __attribute__((ext_vector_type(8))) short bf16x8;
typedef __attribute__((ext_vector_type(4))) float f32x4;

#define KQPRE 0.18033688011112042f   // 0.125 * log2(e), folded into q at gemm1

static __device__ __forceinline__ ushort_t f2bf(float f) {
    union { float f; unsigned int u; } v; v.f = f;
    unsigned int r = v.u + 0x7FFF + ((v.u >> 16) & 1);   // RNE
    return (ushort_t)(r >> 16);
}
static __device__ __forceinline__ float bf2f(ushort_t b) {
    union { unsigned u; float f; } v; v.u = ((unsigned)b) << 16;
    return v.f;
}

static __device__ __forceinline__ unsigned pk_bf16(float lo, float hi) {
    unsigned r;
    asm("v_cvt_pk_bf16_f32 %0, %1, %2" : "=v"(r) : "v"(lo), "v"(hi));
    return r;
}

static __device__ __forceinline__ void gload16(const void* g, void* l) {
    __builtin_amdgcn_global_load_lds(
        (const __attribute__((address_space(1))) void*)g,
        (__attribute__((address_space(3))) void*)l,
        16, 0, 0);
}

// ===========================================================================
// fused fp32 -> bf16 bulk convert for x (4096 blks), Win (1536), Wout (512)
// ===========================================================================
__global__ __launch_bounds__(256)
void cvt3_f32_bf16(const float* __restrict__ x,  ushort_t* __restrict__ xb,
                   const float* __restrict__ Wi, ushort_t* __restrict__ Wib,
                   const float* __restrict__ Wo, ushort_t* __restrict__ Wob)
{
    const int blk = blockIdx.x;
    const float* src; ushort_t* dst; int i;
    if (blk < 4096)      { src = x;  dst = xb;  i = blk * 256 + threadIdx.x; }
    else if (blk < 5632) { src = Wi; dst = Wib; i = (blk - 4096) * 256 + threadIdx.x; }
    else                 { src = Wo; dst = Wob; i = (blk - 5632) * 256 + threadIdx.x; }
    const float4 a = ((const float4*)src)[i * 2];
    const float4 b = ((const float4*)src)[i * 2 + 1];
    union { ushort_t us[8]; uint4 v; } pk;
    pk.us[0] = f2bf(a.x); pk.us[1] = f2bf(a.y); pk.us[2] = f2bf(a.z); pk.us[3] = f2bf(a.w);
    pk.us[4] = f2bf(b.x); pk.us[5] = f2bf(b.y); pk.us[6] = f2bf(b.z); pk.us[7] = f2bf(b.w);
    ((uint4*)dst)[i] = pk.v;
}

// ===========================================================================
// gemm1_256 — verified r17/r19: 256x256 counted-vmcnt pipeline (T3+T4) with
// fused RoPE + q pre-scale epilogue.
// ===========================================================================
__global__ __launch_bounds__(512, 2)
void gemm1_256(const ushort_t* __restrict__ A, const ushort_t* __restrict__ W,
               const float* __restrict__ bias, ushort_t* __restrict__ Cb,
               const float* __restrict__ cosT, const float* __restrict__ sinT)
{
    const int M = NB * NS, N = 3 * NE, K = NE;
    const int NK = K / 64;                    // 16 K-tiles
    __shared__ ushort_t As[2][256 * 64];
    __shared__ ushort_t Bs[2][256 * 64];

    const int tid  = threadIdx.x;
    const int lane = tid & 63;
    const int wid  = tid >> 6;                // 0..7
    const int lr   = lane & 15;
    const int lg   = lane >> 4;
    const int wr   = wid >> 2;                // 0..1 (M half)
    const int wc   = wid & 3;                 // 0..3 (N quarter)

    const int orig = blockIdx.x;
    const int wg   = (orig & 7) * 48 + (orig >> 3);
    const int bx   = wg % 12;
    const int by   = wg / 12;
    const int m0 = by * 256, n0 = bx * 256;
    (void)M; (void)N;

    size_t srcA[4], srcB[4];
    int dstoff[4];
#pragma unroll
    for (int p = 0; p < 4; ++p) {
        const int g   = p * 512 + tid;
        const int row = g >> 3;
        const int cl  = (g & 7) ^ (row & 7);
        srcA[p] = (size_t)(m0 + row) * K + cl * 8;
        srcB[p] = (size_t)(n0 + row) * K + cl * 8;
        dstoff[p] = (p * 512 + wid * 64) * 8;
    }

    const int x7  = lr & 7;
    const int pc0 = ((0 + lg) ^ x7) * 8;
    const int pc1 = ((4 + lg) ^ x7) * 8;
    int offa[8], offb[4];
#pragma unroll
    for (int mf = 0; mf < 8; ++mf) offa[mf] = (wr * 128 + mf * 16 + lr) * 64;
#pragma unroll
    for (int nf = 0; nf < 4; ++nf) offb[nf] = (wc * 64 + nf * 16 + lr) * 64;

    f32x4 acc[8][4];
#pragma unroll
    for (int i = 0; i < 8; ++i)
#pragma unroll
        for (int j = 0; j < 4; ++j) acc[i][j] = (f32x4){0.f, 0.f, 0.f, 0.f};

#pragma unroll
    for (int p = 0; p < 4; ++p) {
        gload16(A + srcA[p], (ushort_t*)As[0] + dstoff[p]);
        gload16(W + srcB[p], (ushort_t*)Bs[0] + dstoff[p]);
    }
#pragma unroll
    for (int p = 0; p < 4; ++p) {
        gload16(A + srcA[p] + 64, (ushort_t*)As[1] + dstoff[p]);
        gload16(W + srcB[p] + 64, (ushort_t*)Bs[1] + dstoff[p]);
    }
    asm volatile("s_waitcnt vmcnt(8)" ::: "memory");
    __builtin_amdgcn_s_barrier();
    __builtin_amdgcn_sched_barrier(0);

    int cur = 0;
    for (int t = 0; t < NK; ++t) {
        bf16x8 af[8], bfv[4];
#pragma unroll
        for (int mf = 0; mf < 8; ++mf) af[mf] = *(const bf16x8*)&As[cur][offa[mf] + pc0];
#pragma unroll
        for (int nf = 0; nf < 4; ++nf) bfv[nf] = *(const bf16x8*)&Bs[cur][offb[nf] + pc0];
        __builtin_amdgcn_s_setprio(1);
#pragma unroll
        for (int mf = 0; mf < 8; ++mf)
#pragma unroll
            for (int nf = 0; nf < 4; ++nf)
                acc[mf][nf] = __builtin_amdgcn_mfma_f32_16x16x32_bf16(
                    af[mf], bfv[nf], acc[mf][nf], 0, 0, 0);
        __builtin_amdgcn_s_setprio(0);
#pragma unroll
        for (int mf = 0; mf < 8; ++mf) af[mf] = *(const bf16x8*)&As[cur][offa[mf] + pc1];
#pragma unroll
        for (int nf = 0; nf < 4; ++nf) bfv[nf] = *(const bf16x8*)&Bs[cur][offb[nf] + pc1];
        asm volatile("s_waitcnt lgkmcnt(0)" ::: "memory");
        __builtin_amdgcn_sched_barrier(0);
        __builtin_amdgcn_s_barrier();
        __builtin_amdgcn_sched_barrier(0);
        if (t + 2 < NK) {
            const int koff = (t + 2) * 64;
#pragma unroll
            for (int p = 0; p < 4; ++p) {
                gload16(A + srcA[p] + koff, (ushort_t*)As[cur] + dstoff[p]);
                gload16(W + srcB[p] + koff, (ushort_t*)Bs[cur] + dstoff[p]);
            }
        }
        __builtin_amdgcn_s_setprio(1);
#pragma unroll
        for (int mf = 0; mf < 8; ++mf)
#pragma unroll
            for (int nf = 0; nf < 4; ++nf)
                acc[mf][nf] = __builtin_amdgcn_mfma_f32_16x16x32_bf16(
                    af[mf], bfv[nf], acc[mf][nf], 0, 0, 0);
        __builtin_amdgcn_s_setprio(0);
        if (t + 1 < NK) {
            if (t + 2 < NK) asm volatile("s_waitcnt vmcnt(8)" ::: "memory");
            else            asm volatile("s_waitcnt vmcnt(0)" ::: "memory");
            __builtin_amdgcn_s_barrier();
            __builtin_amdgcn_sched_barrier(0);
        }
        cur ^= 1;
    }

    const int tt = n0 >> 10;                  // 0=q 1=k 2=v (uniform: 256|1024)
    const int nbase = n0 + wc * 64;           // wave's 64-col slice = one head
    const int h = (nbase >> 6) & (NH - 1);
    float bj[4];
#pragma unroll
    for (int nf = 0; nf < 4; ++nf) bj[nf] = bias[nbase + nf * 16 + lr];
#pragma unroll
    for (int mf = 0; mf < 8; ++mf)
#pragma unroll
        for (int r = 0; r < 4; ++r) {
            const int m = m0 + wr * 128 + mf * 16 + lg * 4 + r;
            const int b = m >> 11;
            const int s = m & (NS - 1);
            float v[4];
#pragma unroll
            for (int nf = 0; nf < 4; ++nf) v[nf] = acc[mf][nf][r] + bj[nf];
            if (tt < 2) {                     // RoPE on q,k (fp32, pre-round)
#pragma unroll
                for (int p = 0; p < 2; ++p) {
                    const int d = p * 16 + lr;           // < 32
                    const float c  = cosT[s * ND + d];   // table halves duplicated
                    const float sn = sinT[s * ND + d];
                    const float lo = v[p] * c - v[p + 2] * sn;
                    const float hi = v[p + 2] * c + v[p] * sn;
                    v[p] = lo; v[p + 2] = hi;
                }
                if (tt == 0) {                // q *= 0.125*log2e — once
#pragma unroll
                    for (int nf = 0; nf < 4; ++nf) v[nf] *= KQPRE;
                }
            }
#pragma unroll
            for (int nf = 0; nf < 4; ++nf)
                Cb[((size_t)((tt * NB + b) * NH + h) * NS + s) * ND
                   + nf * 16 + lr] = f2bf(v[nf]);
        }
}

// ===========================================================================
// bf16 MFMA GEMM (m97 structure) — verified; used for gemm2 (EPI=0).
// ===========================================================================
template<int EPI>
__global__ __launch_bounds__(256)
void gemm_bf16(const ushort_t* __restrict__ A, const ushort_t* __restrict__ W,
               const float* __restrict__ bias, float* __restrict__ C,
               ushort_t* __restrict__ Cb, const float* __restrict__ cosT,
               const float* __restrict__ sinT, int M, int N, int K)
{
    __shared__ ushort_t As[128 * 32];
    __shared__ ushort_t Bs[128 * 32];
    const int tid  = threadIdx.x;
    const int lane = tid & 63;
    const int wid  = tid >> 6;
    const int lr   = lane & 15;
    const int lg   = lane >> 4;

    const int lin   = blockIdx.y * gridDim.x + blockIdx.x;
    const int chunk = (gridDim.x * gridDim.y) >> 3;
    const int lin2  = (lin & 7) * chunk + (lin >> 3);
    const int bx    = lin2 % gridDim.x;
    const int by    = lin2 / gridDim.x;
    const int m0 = by * 128;
    const int n0 = bx * 128;
    const int wr = wid >> 1, wc = wid & 1;

    size_t srcoff[2];
    int ldsoff[2];
#pragma unroll
    for (int p = 0; p < 2; ++p) {
        const int chnk = p * 256 + tid;
        const int row = chnk >> 2;
        const int sp  = chnk & 3;
        const int c   = sp ^ ((row >> 1) & 3);
        srcoff[p] = (size_t)row * K + c * 8;
        ldsoff[p] = (p * 256 + wid * 64) * 8;
    }
    const ushort_t* Ag = A + (size_t)m0 * K;
    const ushort_t* Wg = W + (size_t)n0 * K;

    int offa[4], offb[4];
#pragma unroll
    for (int f = 0; f < 4; ++f) {
        const int ra = wr * 64 + f * 16 + lr;
        offa[f] = ra * 32 + (lg ^ ((ra >> 1) & 3)) * 8;
        const int rb = wc * 64 + f * 16 + lr;
        offb[f] = rb * 32 + (lg ^ ((rb >> 1) & 3)) * 8;
    }

    f32x4 acc[4][4];
#pragma unroll
    for (int i = 0; i < 4; ++i)
#pragma unroll
        for (int j = 0; j < 4; ++j) acc[i][j] = (f32x4){0.f, 0.f, 0.f, 0.f};

    for (int k0 = 0; k0 < K; k0 += 32) {
        __syncthreads();
#pragma unroll
        for (int p = 0; p < 2; ++p) {
            gload16(Ag + srcoff[p] + k0, (ushort_t*)As + ldsoff[p]);
            gload16(Wg + srcoff[p] + k0, (ushort_t*)Bs + ldsoff[p]);
        }
        __syncthreads();
        bf16x8 af[4], bfr[4];
#pragma unroll
        for (int f = 0; f < 4; ++f) {
            af[f]  = *(const bf16x8*)&As[offa[f]];
            bfr[f] = *(const bf16x8*)&Bs[offb[f]];
        }
#pragma unroll
        for (int mf = 0; mf < 4; ++mf)
#pragma unroll
            for (int nf = 0; nf < 4; ++nf)
                acc[mf][nf] = __builtin_amdgcn_mfma_f32_16x16x32_bf16(
                    af[mf], bfr[nf], acc[mf][nf], 0, 0, 0);
    }

    if (EPI == 0) {
#pragma unroll
        for (int nf = 0; nf < 4; ++nf) {
            const int n = n0 + wc * 64 + nf * 16 + lr;
            const float bj = bias[n];
#pragma unroll
            for (int mf = 0; mf < 4; ++mf)
#pragma unroll
                for (int r = 0; r < 4; ++r) {
                    const int m = m0 + wr * 64 + mf * 16 + lg * 4 + r;
                    C[(size_t)m * N + n] = acc[mf][nf][r] + bj;
                }
        }
    } else {
        const int tt = n0 >> 10;
        float bj[4]; int hh[4];
#pragma unroll
        for (int nf = 0; nf < 4; ++nf) {
            const int n = n0 + wc * 64 + nf * 16 + lr;
            bj[nf] = bias[n];
            hh[nf] = (n >> 6) & (NH - 1);
        }
#pragma unroll
        for (int mf = 0; mf < 4; ++mf)
#pragma unroll
            for (int r = 0; r < 4; ++r) {
                const int m = m0 + wr * 64 + mf * 16 + lg * 4 + r;
                const int b = m >> 11;
                const int s = m & (NS - 1);
                float v[4];
#pragma unroll
                for (int nf = 0; nf < 4; ++nf) v[nf] = acc[mf][nf][r] + bj[nf];
                if (tt < 2) {
#pragma unroll
                    for (int p = 0; p < 2; ++p) {
                        const int d = p * 16 + lr;
                        const float c  = cosT[s * ND + d];
                        const float sn = sinT[s * ND + d];
                        const float lo = v[p] * c - v[p + 2] * sn;
                        const float hi = v[p + 2] * c + v[p] * sn;
                        v[p] = lo; v[p + 2] = hi;
                    }
                    if (tt == 0) {
#pragma unroll
                        for (int nf = 0; nf < 4; ++nf) v[nf] *= KQPRE;
                    }
                }
#pragma unroll
                for (int nf = 0; nf < 4; ++nf)
                    Cb[((size_t)((tt * NB + b) * NH + hh[nf]) * NS + s) * ND
                       + nf * 16 + lr] = f2bf(v[nf]);
            }
    }
}

// ===========================================================================
// Swapped-operand bf16 MFMA flash attention — r13/r16/r17/r19-verbatim
// (verified): packed-P LDS path, ones-MFMA rowsum, exp2 softmax (scale
// pre-folded into q), B3-as-fence, T1 XCD swizzle, T5 setprio, T14 prefetch.
// ===========================================================================
__global__ __launch_bounds__(256)
void attn_kernel(const ushort_t* __restrict__ qkvb, ushort_t* __restrict__ obuf)
{
    __shared__ ushort_t Ks[64 * 72];
    __shared__ ushort_t Vs[64 * 64];
    __shared__ ushort_t Ps[128 * 72];

    const int tid  = threadIdx.x;
    const int lane = tid & 63;
    const int wid  = tid >> 6;
    const int lr   = lane & 15;
    const int lg   = lane >> 4;

    const int orig = blockIdx.x;                 // 0..1023
    const int wg   = (orig & 7) * 128 + (orig >> 3);
    const int bh   = wg >> 4;
    const int b = bh >> 4, h = bh & (NH - 1);
    const int q0 = (wg & 15) * 128;

    const ushort_t* qbase = qkvb + ((size_t)((0 * NB + b) * NH + h)) * (NS * ND);
    const ushort_t* kbase = qkvb + ((size_t)((1 * NB + b) * NH + h)) * (NS * ND);
    const ushort_t* vbase = qkvb + ((size_t)((2 * NB + b) * NH + h)) * (NS * ND);

    bf16x8 onesf;
#pragma unroll
    for (int j = 0; j < 8; ++j) onesf[j] = (short)0x3F80;

    bf16x8 qf[2][2];
#pragma unroll
    for (int st = 0; st < 2; ++st)
#pragma unroll
        for (int kh = 0; kh < 2; ++kh)
            qf[st][kh] = *(const bf16x8*)(qbase + (size_t)(q0 + wid * 32 + st * 16 + lr) * ND
                                          + kh * 32 + lg * 8);

    const int sc = tid & 7;
    const int sr0 = tid >> 3;

    uint4 krg[2], vrg[2];
#pragma unroll
    for (int it = 0; it < 2; ++it) {
        const int r = sr0 + it * 32;
        krg[it] = *(const uint4*)(kbase + r * ND + sc * 8);
        vrg[it] = *(const uint4*)(vbase + r * ND + sc * 8);
    }

    f32x4 acc_o[2][4];
    f32x4 acc_l[2];
#pragma unroll
    for (int st = 0; st < 2; ++st) {
        acc_l[st] = (f32x4){0.f, 0.f, 0.f, 0.f};
#pragma unroll
        for (int dk = 0; dk < 4; ++dk) acc_o[st][dk] = (f32x4){0.f, 0.f, 0.f, 0.f};
    }

    for (int kt = 0; kt < NS; kt += KVB) {
        __syncthreads();                         // B1: prev tile reads done
#pragma unroll
        for (int it = 0; it < 2; ++it) {
            const int r = sr0 + it * 32;
            *(uint4*)&Ks[r * 72 + sc * 8] = krg[it];
            union { uint4 v; ushort_t us[8]; } pu;
            pu.v = vrg[it];
#pragma unroll
            for (int j = 0; j < 8; ++j) {
                const int sw = (j ^ sc) << 4;
                Vs[(sc * 8 + j) * 64 + ((((r * 2) ^ sw)) >> 1)] = pu.us[j];
            }
        }
        __syncthreads();                         // B2: staging visible
        if (kt + KVB < NS) {
#pragma unroll
            for (int it = 0; it < 2; ++it) {
                const int r = kt + KVB + sr0 + it * 32;
                krg[it] = *(const uint4*)(kbase + (size_t)r * ND + sc * 8);
                vrg[it] = *(const uint4*)(vbase + (size_t)r * ND + sc * 8);
            }
        }

        f32x4 s[2][4];
#pragma unroll
        for (int st = 0; st < 2; ++st)
#pragma unroll
            for (int kvf = 0; kvf < 4; ++kvf) s[st][kvf] = (f32x4){0.f, 0.f, 0.f, 0.f};
        __builtin_amdgcn_s_setprio(1);
#pragma unroll
        for (int kh = 0; kh < 2; ++kh)
#pragma unroll
            for (int kvf = 0; kvf < 4; ++kvf) {
                const bf16x8 kf = *(const bf16x8*)&Ks[(kvf * 16 + lr) * 72 + kh * 32 + lg * 8];
                s[0][kvf] = __builtin_amdgcn_mfma_f32_16x16x32_bf16(kf, qf[0][kh], s[0][kvf], 0, 0, 0);
                s[1][kvf] = __builtin_amdgcn_mfma_f32_16x16x32_bf16(kf, qf[1][kh], s[1][kvf], 0, 0, 0);
            }
        __builtin_amdgcn_s_setprio(0);

#pragma unroll
        for (int st = 0; st < 2; ++st) {
            const int prow = (wid * 32 + st * 16 + lr) * 72;
#pragma unroll
            for (int kvf = 0; kvf < 4; ++kvf) {
                const float p0 = __builtin_amdgcn_exp2f(s[st][kvf][0]);
                const float p1 = __builtin_amdgcn_exp2f(s[st][kvf][1]);
                const float p2 = __builtin_amdgcn_exp2f(s[st][kvf][2]);
                const float p3 = __builtin_amdgcn_exp2f(s[st][kvf][3]);
                const unsigned w01 = pk_bf16(p0, p1);
                const unsigned w23 = pk_bf16(p2, p3);
                *(uint2*)&Ps[prow + kvf * 16 + lg * 4] = make_uint2(w01, w23);
            }
        }
        asm volatile("s_waitcnt lgkmcnt(0)" ::: "memory");
        __builtin_amdgcn_sched_barrier(0);

        __builtin_amdgcn_s_setprio(1);
#pragma unroll
        for (int kh = 0; kh < 2; ++kh) {
            const bf16x8 pf0 = *(const bf16x8*)&Ps[(wid * 32 + 0  + lr) * 72 + kh * 32 + lg * 8];
            const bf16x8 pf1 = *(const bf16x8*)&Ps[(wid * 32 + 16 + lr) * 72 + kh * 32 + lg * 8];
            acc_l[0] = __builtin_amdgcn_mfma_f32_16x16x32_bf16(pf0, onesf, acc_l[0], 0, 0, 0);
            acc_l[1] = __builtin_amdgcn_mfma_f32_16x16x32_bf16(pf1, onesf, acc_l[1], 0, 0, 0);
#pragma unroll
            for (int dk = 0; dk < 4; ++dk) {
                const int d = dk * 16 + lr;
                const int sw = ((d & 7) ^ ((d >> 3) & 7)) << 4;
                const bf16x8 vf = *(const bf16x8*)&Vs[d * 64 + (((kh * 64 + lg * 16) ^ sw) >> 1)];
                acc_o[0][dk] = __builtin_amdgcn_mfma_f32_16x16x32_bf16(pf0, vf, acc_o[0][dk], 0, 0, 0);
                acc_o[1][dk] = __builtin_amdgcn_mfma_f32_16x16x32_bf16(pf1, vf, acc_o[1][dk], 0, 0, 0);
            }
        }
        __builtin_amdgcn_s_setprio(0);
    }

#pragma unroll
    for (int st = 0; st < 2; ++st) {
        float invq[4];
#pragma unroll
        for (int reg = 0; reg < 4; ++reg)
            invq[reg] = 1.0f / acc_l[st][reg];
#pragma unroll
        for (int dk = 0; dk < 4; ++dk)
#pragma unroll
            for (int reg = 0; reg < 4; ++reg) {
                const int q = q0 + wid * 32 + st * 16 + lg * 4 + reg;
                const int d = dk * 16 + lr;
                obuf[((size_t)(b * NS + q)) * NE + h * ND + d] =
                    f2bf(acc_o[st][dk][reg] * invq[reg]);
            }
    }
}

// ===========================================================================
extern "C" void kernel_launch(void* const* d_in, const int* in_sizes, int n_in,
                              void* d_out, int out_size, void* d_ws, size_t ws_size,
                              hipStream_t stream)
{
    const float* x    = (const float*)d_in[0];
    const float* Win  = (const float*)d_in[1];
    const float* bin  = (const float*)d_in[2];
    const float* Wout = (const float*)d_in[3];
    const float* bout = (const float*)d_in[4];
    const float* cosT = (const float*)d_in[5];
    const float* sinT = (const float*)d_in[6];
    float* out  = (float*)d_out;

    ushort_t* qkvb  = (ushort_t*)d_ws;
    ushort_t* obufb = qkvb + (size_t)3 * NB * NH * NS * ND;
    ushort_t* xb    = obufb + (size_t)NB * NS * NE;
    ushort_t* Wib   = xb + (size_t)NB * NS * NE;
    ushort_t* Wob   = Wib + (size_t)3 * NE * NE;

    cvt3_f32_bf16<<<6144, 256, 0, stream>>>(x, xb, Win, Wib, Wout, Wob);

    // 1) QKV projection (256^2 counted-vmcnt pipeline) + fused RoPE + q scale
    gemm1_256<<<384, 512, 0, stream>>>(xb, Wib, bin, qkvb, cosT, sinT);
    // 2) attention (verified) -> bf16 obuf [B][S][E]
    attn_kernel<<<dim3(NB * NH * (NS / 128)), 256, 0, stream>>>(qkvb, obufb);
    // 3) output projection (m97 structure, verified)
    gemm_bf16<0><<<dim3(NE / 128, NB * NS / 128), 256, 0, stream>>>(
        obufb, Wob, bout, out, nullptr, nullptr, nullptr, NB * NS, NE, NE);
}